// Round 5
// baseline (5524.939 us; speedup 1.0000x reference)
//
#include <hip/hip_runtime.h>

// HSMM forward log-likelihood, B=32, T=8192, K=128, Dmax=128.
// One block per sequence (32 blocks, 512 threads = 8 waves).
// Probability-space recursion with per-step scalar renorm and a per-state
// gauge psi so ring-buffer entries are write-once.
//
// R5 = verified R1 base + {no-vmcnt-drain barrier, launch_bounds(512,1),
//      Mp clamp}. Max renorm is 1-STEP delayed (R1 form): the 2-step delay
//      used in R2-R4 is an undamped oscillator (x_t = x_{t-1} - x_{t-2} + b_t,
//      |roots| = 1) whose noise-driven amplitude ~ sqrt(T) ~ 90 nats
//      overflows f32 -> NaN. 1-step delay is deadbeat (x_t = b_t), stable.
//
// Thread layout: lane L (0..63), wave w (0..7):
//   j = (L&15) + 16*w   (owned state, 128 total)
//   c = L>>4            (reduction chunk 0..3)

#define T_LEN 8192
#define KST   128
#define NTHR  512

__device__ __forceinline__ void barrier_nodrain() {
  // LDS producer->consumer visibility needs lgkmcnt(0)+barrier only; global
  // prefetch loads (vmcnt) stay in flight across the barrier.
  asm volatile("s_waitcnt lgkmcnt(0)\n\ts_barrier" ::: "memory");
}

__global__ __launch_bounds__(NTHR, 1) void hsmm_fwd_kernel(
    const float* __restrict__ logB_all,
    const float* __restrict__ logpi,
    const float* __restrict__ logA,
    const float* __restrict__ logD,
    float* __restrict__ out)
{
  const int tid = threadIdx.x;
  const int L   = tid & 63;
  const int w   = tid >> 6;
  const int jj  = (L & 15) + 16 * w;   // owned state
  const int c   = L >> 4;              // chunk 0..3
  const int b   = blockIdx.x;
  const float* __restrict__ logB = logB_all + (size_t)b * T_LEN * KST;

  __shared__ float expD_t[128][KST];   // [d][j]; row 0 zeroed (stale-slot kill)
  __shared__ float s_lds[2][KST];      // shat exchange, double buffered
  __shared__ float m_lds[2][8];        // per-wave maxes, double buffered
  __shared__ float fin[8];

  // ---- init: transposed expD table (row0 = 0), s/m buffers ----
  for (int idx = tid; idx < 128 * KST; idx += NTHR) {
    int d = idx >> 7, j0 = idx & 127;
    expD_t[d][j0] = (d == 0) ? 0.0f : __expf(logD[j0 * 128 + d]);
  }
  if (tid < KST) s_lds[0][tid] = 0.0f;
  if (tid < 8) { m_lds[0][tid] = 1.0f; m_lds[1][tid] = 1.0f; }

  // ---- per-thread constants ----
  float aA[16], aB[16];
#pragma unroll
  for (int k = 0; k < 16; ++k) {
    aA[k] = __expf(logA[(16 * c + k) * KST + jj]);
    aB[k] = __expf(logA[(64 + 16 * c + k) * KST + jj]);
  }
  const float expD0 = __expf(logD[jj * 128 + 0]);
  const float pexp  = __expf(logpi[jj]);

  float QA[16], QB[16];
#pragma unroll
  for (int k = 0; k < 16; ++k) { QA[k] = 0.0f; QB[k] = 0.0f; }

  __syncthreads();  // expD_t ready

  // expD window init for t=0: slot k -> reg k holds expD[(0 - p)&127]
  float eA[16], eB[16];
#pragma unroll
  for (int k = 0; k < 16; ++k) {
    eA[k] = expD_t[(-(16 * c + k)) & 127][jj];
    eB[k] = expD_t[(-(64 + 16 * c + k)) & 127][jj];
  }

  // log_B prefetch ring
  float lb[16];
#pragma unroll
  for (int u = 0; u < 16; ++u) lb[u] = logB[u * KST + jj];

  float psi  = 1.0f;   // e^{cB[t+1,j] - C_t - gamma_j}
  float Ctot = 0.0f;   // running C (sum of log M)
  float s_keep = 0.0f;

#pragma unroll 1
  for (int t0 = 0; t0 < T_LEN; t0 += 16) {
#pragma unroll
    for (int u = 0; u < 16; ++u) {
      const int t = t0 + u;

      // (1) previous step's global max M (8 wave maxes, broadcast reads)
      float4 mm0 = *(const float4*)&m_lds[u & 1][0];
      float4 mm1 = *(const float4*)&m_lds[u & 1][4];
      float Mp = fmaxf(fmaxf(fmaxf(mm0.x, mm0.y), fmaxf(mm0.z, mm0.w)),
                       fmaxf(fmaxf(mm1.x, mm1.y), fmaxf(mm1.z, mm1.w)));
      Mp = fminf(fmaxf(Mp, 1e-30f), 1e30f);  // exact (free gauge); NaN firewall
      float rMp = __builtin_amdgcn_rcpf(Mp);
      Ctot += __logf(Mp);

      // (2) shat(t-1) reads for matvec (quarter-uniform b128 reads)
      const float4* sp = (const float4*)&s_lds[u & 1][0];
      float4 sA0 = sp[4 * c + 0], sA1 = sp[4 * c + 1];
      float4 sA2 = sp[4 * c + 2], sA3 = sp[4 * c + 3];
      float4 sB0 = sp[16 + 4 * c + 0], sB1 = sp[16 + 4 * c + 1];
      float4 sB2 = sp[16 + 4 * c + 2], sB3 = sp[16 + 4 * c + 3];

      // (3) duration dot over ring slots (stale slot has e == 0)
      float dp = 0.0f;
#pragma unroll
      for (int k = 0; k < 16; ++k) {
        dp = fmaf(QA[k], eA[(k - u) & 15], dp);
        dp = fmaf(QB[k], eB[(k - u) & 15], dp);
      }

      // (4) psi update (gauge carries emissions + renorm)
      float expB   = __expf(lb[u]);
      float invpsi = __builtin_amdgcn_rcpf(psi);  // 1/psi_{t-1}
      psi = psi * expB * rMp;

      // (5) matvec partial: chunk [16c,16c+16) and [64+16c, 64+16c+16)
      float mp = 0.0f;
      mp = fmaf(aA[0], sA0.x, mp);  mp = fmaf(aA[1], sA0.y, mp);
      mp = fmaf(aA[2], sA0.z, mp);  mp = fmaf(aA[3], sA0.w, mp);
      mp = fmaf(aA[4], sA1.x, mp);  mp = fmaf(aA[5], sA1.y, mp);
      mp = fmaf(aA[6], sA1.z, mp);  mp = fmaf(aA[7], sA1.w, mp);
      mp = fmaf(aA[8], sA2.x, mp);  mp = fmaf(aA[9], sA2.y, mp);
      mp = fmaf(aA[10], sA2.z, mp); mp = fmaf(aA[11], sA2.w, mp);
      mp = fmaf(aA[12], sA3.x, mp); mp = fmaf(aA[13], sA3.y, mp);
      mp = fmaf(aA[14], sA3.z, mp); mp = fmaf(aA[15], sA3.w, mp);
      mp = fmaf(aB[0], sB0.x, mp);  mp = fmaf(aB[1], sB0.y, mp);
      mp = fmaf(aB[2], sB0.z, mp);  mp = fmaf(aB[3], sB0.w, mp);
      mp = fmaf(aB[4], sB1.x, mp);  mp = fmaf(aB[5], sB1.y, mp);
      mp = fmaf(aB[6], sB1.z, mp);  mp = fmaf(aB[7], sB1.w, mp);
      mp = fmaf(aB[8], sB2.x, mp);  mp = fmaf(aB[9], sB2.y, mp);
      mp = fmaf(aB[10], sB2.z, mp); mp = fmaf(aB[11], sB2.w, mp);
      mp = fmaf(aB[12], sB3.x, mp); mp = fmaf(aB[13], sB3.y, mp);
      mp = fmaf(aB[14], sB3.z, mp); mp = fmaf(aB[15], sB3.w, mp);

      // (6) intra-wave chunk reduction (c lives on lane bits 4,5)
      dp += __shfl_xor(dp, 16); dp += __shfl_xor(dp, 32);
      mp += __shfl_xor(mp, 16); mp += __shfl_xor(mp, 32);

      // (7) insert value: Qins = mv * invpsi  (M factors cancel exactly)
      float Qins = (t == 0) ? pexp : mp * invpsi;

      // (8) shat_t = (dot + Qins*expD[j,0]) * psi_t
      float s = fmaf(Qins, expD0, dp) * psi;

      // (9) ring insert (slot p = t&127; static reg index u)
      if (((t >> 4) & 7) == c)     QA[u] = Qins;
      if (((t >> 4) & 7) == c + 4) QB[u] = Qins;

      // (10) in-wave max over this wave's 16 states (lane bits 0..3)
      float sm = s;
      sm = fmaxf(sm, __shfl_xor(sm, 1));
      sm = fmaxf(sm, __shfl_xor(sm, 2));
      sm = fmaxf(sm, __shfl_xor(sm, 4));
      sm = fmaxf(sm, __shfl_xor(sm, 8));

      // (11) publish to next step's buffers (1-step delay: STABLE)
      if (L == 0) m_lds[(u + 1) & 1][w] = sm;
      if (c == 0) s_lds[(u + 1) & 1][jj] = s;

      // (12) expD window rotation: one fresh value per run
      eA[(-(u + 1)) & 15] = expD_t[(t + 1 - 16 * c) & 127][jj];
      eB[(-(u + 1)) & 15] = expD_t[(t + 1 - 64 - 16 * c) & 127][jj];

      // (13) log_B prefetch 16 ahead (clamped; tail values unused)
      int tn = t + 16; tn = (tn < T_LEN) ? tn : (T_LEN - 1);
      lb[u] = logB[tn * KST + jj];

      // (14) gauge renorm every 16 steps: fold psi_t into Q, reset psi
      if (u == 15) {
#pragma unroll
        for (int k = 0; k < 16; ++k) { QA[k] *= psi; QB[k] *= psi; }
        psi = 1.0f;
      }

      s_keep = s;
      barrier_nodrain();
    }
  }

  // ---- final: out[b] = C_{T-1} + log sum_j shat_{T-1}[j] ----
  float ssum = s_keep;
  ssum += __shfl_xor(ssum, 1);
  ssum += __shfl_xor(ssum, 2);
  ssum += __shfl_xor(ssum, 4);
  ssum += __shfl_xor(ssum, 8);
  if (L == 0) fin[w] = ssum;
  __syncthreads();
  if (tid == 0) {
    float tot = 0.0f;
#pragma unroll
    for (int i = 0; i < 8; ++i) tot += fin[i];
    out[b] = Ctot + __logf(tot);
  }
}

extern "C" void kernel_launch(void* const* d_in, const int* in_sizes, int n_in,
                              void* d_out, int out_size, void* d_ws, size_t ws_size,
                              hipStream_t stream) {
  const float* logB  = (const float*)d_in[0];
  const float* logpi = (const float*)d_in[1];
  const float* logA  = (const float*)d_in[2];
  const float* logD  = (const float*)d_in[3];
  float* out = (float*)d_out;
  const int B = out_size;  // 32
  hipLaunchKernelGGL(hsmm_fwd_kernel, dim3(B), dim3(NTHR), 0, stream,
                     logB, logpi, logA, logD, out);
}

// Round 6
// 5361.364 us; speedup vs baseline: 1.0305x; 1.0305x over previous
//
#include <hip/hip_runtime.h>

// HSMM forward log-likelihood, B=32, T=8192, K=128, Dmax=128.
// One block per sequence (32 blocks, 512 threads = 8 waves).
// Probability-space recursion, per-state gauge psi (write-once ring slots),
// 1-step-delayed global-max renorm (deadbeat, stable; 2-step delay is an
// undamped oscillator -> NaN, learned R2-R4).
//
// R6: DPP everywhere. Lane layout: c = L&3 (chunk, quad lanes), state
// jj = (L>>2) + 16w. Chunk reduce = quad_perm DPP butterflies; wave max =
// row mirrors + row_bcast15/31 (lane 63 writes). dp/mp use 4-acc trees.
// exp(logB) and rcp(psi) hoisted off the critical path. Step bodies are
// template<int U> -> all register-array indices compile-time constants.

#define T_LEN 8192
#define KST   128
#define NTHR  512
#define SROW  160   // skewed shat row: addr(j) = j + 8*(j>>5) <= 151 < 160

__device__ __forceinline__ void barrier_nodrain() {
  // LDS producer->consumer needs lgkmcnt(0)+barrier only; global prefetch
  // loads (vmcnt) stay in flight across the barrier.
  asm volatile("s_waitcnt lgkmcnt(0)\n\ts_barrier" ::: "memory");
}

// DPP move: result = src permuted by CTRL; invalid source lanes -> 0.
template <int CTRL>
__device__ __forceinline__ float dpp_mov(float x) {
  int y = __builtin_amdgcn_update_dpp(0, __builtin_bit_cast(int, x),
                                      CTRL, 0xF, 0xF, true);
  return __builtin_bit_cast(float, y);
}

template <int U>
__device__ __forceinline__ void step_body(
    int t0, int c, int jj, int w, int L,
    const float* __restrict__ pB,
    float (&QA)[16], float (&QB)[16],
    const float (&aA)[16], const float (&aB)[16],
    float (&eA)[16], float (&eB)[16],
    float (&lb)[16],
    float& psi, float& invpsi, float& exq, float& Ctot, float& s_keep,
    float expD0, float pexp,
    float (*s_lds)[SROW], float (*m_lds)[8],
    const float (*expD_t)[KST])
{
  const int t = t0 + U;

  // emission factor for THIS step (exp computed last step, off-path)
  const float expB = exq;

  // (a) prefetch logB t+16 (stays in flight across barriers)
  int tn = t + 16; tn = (tn < T_LEN) ? tn : (T_LEN - 1);
  lb[U] = pB[(size_t)tn * KST];

  // (b) expD rotation reads for NEXT step (temps; eA/eB still live)
  const int rowA = (t + 1 - 32 * c) & 127;
  const int rowB = (rowA - 16) & 127;
  const float neA = expD_t[rowA][jj];
  const float neB = expD_t[rowB][jj];

  // (c) previous step's wave maxes (broadcast b128 reads)
  const float4 mm0 = *(const float4*)&m_lds[U & 1][0];
  const float4 mm1 = *(const float4*)&m_lds[U & 1][4];

  // (d) shat(t-1) for this chunk's 32 states (skewed, bank-disjoint)
  const float* sp = &s_lds[U & 1][40 * c];
  const float4 s0 = *(const float4*)(sp + 0),  s1 = *(const float4*)(sp + 4);
  const float4 s2 = *(const float4*)(sp + 8),  s3 = *(const float4*)(sp + 12);
  const float4 s4 = *(const float4*)(sp + 16), s5 = *(const float4*)(sp + 20);
  const float4 s6 = *(const float4*)(sp + 24), s7 = *(const float4*)(sp + 28);

  // (e) duration dot: register-only 4-acc trees (overlaps LDS latency)
  float d0 = 0.f, d1 = 0.f, d2 = 0.f, d3 = 0.f;
#pragma unroll
  for (int k = 0; k < 8; ++k) {
    d0 = fmaf(QA[k],     eA[(k - U) & 15],     d0);
    d1 = fmaf(QA[k + 8], eA[(k + 8 - U) & 15], d1);
    d2 = fmaf(QB[k],     eB[(k - U) & 15],     d2);
    d3 = fmaf(QB[k + 8], eB[(k + 8 - U) & 15], d3);
  }
  float dp = (d0 + d1) + (d2 + d3);

  // (f) gauge: Mp from step t-1 (clamp = exact free gauge + NaN firewall)
  float Mp = fmaxf(fmaxf(fmaxf(mm0.x, mm0.y), fmaxf(mm0.z, mm0.w)),
                   fmaxf(fmaxf(mm1.x, mm1.y), fmaxf(mm1.z, mm1.w)));
  Mp = fminf(fmaxf(Mp, 1e-30f), 1e30f);
  const float rMp = __builtin_amdgcn_rcpf(Mp);
  Ctot += __logf(Mp);
  psi = psi * expB * rMp;

  // (g) matvec partial: 4-acc trees over this chunk's 32 source states
  float m0 = 0.f, m1 = 0.f, m2 = 0.f, m3 = 0.f;
  m0 = fmaf(aA[0],  s0.x, m0); m0 = fmaf(aA[1],  s0.y, m0);
  m0 = fmaf(aA[2],  s0.z, m0); m0 = fmaf(aA[3],  s0.w, m0);
  m0 = fmaf(aA[4],  s1.x, m0); m0 = fmaf(aA[5],  s1.y, m0);
  m0 = fmaf(aA[6],  s1.z, m0); m0 = fmaf(aA[7],  s1.w, m0);
  m1 = fmaf(aA[8],  s2.x, m1); m1 = fmaf(aA[9],  s2.y, m1);
  m1 = fmaf(aA[10], s2.z, m1); m1 = fmaf(aA[11], s2.w, m1);
  m1 = fmaf(aA[12], s3.x, m1); m1 = fmaf(aA[13], s3.y, m1);
  m1 = fmaf(aA[14], s3.z, m1); m1 = fmaf(aA[15], s3.w, m1);
  m2 = fmaf(aB[0],  s4.x, m2); m2 = fmaf(aB[1],  s4.y, m2);
  m2 = fmaf(aB[2],  s4.z, m2); m2 = fmaf(aB[3],  s4.w, m2);
  m2 = fmaf(aB[4],  s5.x, m2); m2 = fmaf(aB[5],  s5.y, m2);
  m2 = fmaf(aB[6],  s5.z, m2); m2 = fmaf(aB[7],  s5.w, m2);
  m3 = fmaf(aB[8],  s6.x, m3); m3 = fmaf(aB[9],  s6.y, m3);
  m3 = fmaf(aB[10], s6.z, m3); m3 = fmaf(aB[11], s6.w, m3);
  m3 = fmaf(aB[12], s7.x, m3); m3 = fmaf(aB[13], s7.y, m3);
  m3 = fmaf(aB[14], s7.z, m3); m3 = fmaf(aB[15], s7.w, m3);
  float mp = (m0 + m1) + (m2 + m3);

  // (h) cross-chunk reduce on lane bits 0,1: quad_perm DPP butterflies
  dp += dpp_mov<0xB1>(dp);  dp += dpp_mov<0x4E>(dp);   // xor1, xor2
  mp += dpp_mov<0xB1>(mp);  mp += dpp_mov<0x4E>(mp);

  // (i) insert value (M factors cancel exactly); s_hat
  const float Qins = (t == 0) ? pexp : mp * invpsi;
  const float s = fmaf(Qins, expD0, dp) * psi;

  // (j) exp for NEXT step (value loaded 15 steps ago -> long arrived)
  exq = __expf(lb[(U + 1) & 15]);

  // (k) ring insert: slot p = t&127 -> chunk (t>>5)&3, half (t>>4)&1, reg U
  if (((t >> 5) & 3) == c) {
    if ((t >> 4) & 1) QB[U] = Qins; else QA[U] = Qins;
  }

  // (l) wave max over 16 states (s is quad-uniform; values >= 0 so the
  //     bound_ctrl zero-fill of bcast15/31 is harmless under fmax)
  float sm = fmaxf(s, dpp_mov<0x141>(s));    // row_half_mirror == xor4 here
  sm = fmaxf(sm, dpp_mov<0x140>(sm));        // row_mirror      == xor8 here
  sm = fmaxf(sm, dpp_mov<0x142>(sm));        // row_bcast15: rows 1,3 absorb 0,2
  sm = fmaxf(sm, dpp_mov<0x143>(sm));        // row_bcast31: lane 63 = full max
  if (L == 63) m_lds[(U + 1) & 1][w] = sm;

  // (m) publish shat (one lane per state), skewed conflict-free
  if (c == 0) s_lds[(U + 1) & 1][jj + 8 * (jj >> 5)] = s;

  // (n) commit expD window rotation (old values fully consumed in (e))
  eA[(15 - U) & 15] = neA;
  eB[(15 - U) & 15] = neB;

  // (o) gauge renorm every 16 steps: fold psi into ring, reset
  if (U == 15) {
#pragma unroll
    for (int k = 0; k < 16; ++k) { QA[k] *= psi; QB[k] *= psi; }
    psi = 1.0f;
  }

  // (p) 1/psi for next step (off-path here)
  invpsi = __builtin_amdgcn_rcpf(psi);

  s_keep = s;
  barrier_nodrain();
}

__global__ __launch_bounds__(NTHR, 1) void hsmm_fwd_kernel(
    const float* __restrict__ logB_all,
    const float* __restrict__ logpi,
    const float* __restrict__ logA,
    const float* __restrict__ logD,
    float* __restrict__ out)
{
  const int tid = threadIdx.x;
  const int L   = tid & 63;
  const int w   = tid >> 6;
  const int c   = L & 3;          // chunk (quad lanes -> DPP reduce)
  const int jl  = L >> 2;         // 0..15
  const int jj  = jl + 16 * w;    // owned state
  const int b   = blockIdx.x;
  const float* __restrict__ pB = logB_all + (size_t)b * T_LEN * KST + jj;

  __shared__ __align__(16) float expD_t[128][KST];  // [d][j]; row 0 zeroed
  __shared__ __align__(16) float s_lds[2][SROW];    // shat exchange, skewed
  __shared__ __align__(16) float m_lds[2][8];       // wave maxes, dbuf
  __shared__ __align__(16) float fin[8];

  // ---- init: transposed expD table (row0 = 0), s/m buffers ----
  for (int idx = tid; idx < 128 * KST; idx += NTHR) {
    int d = idx >> 7, j0 = idx & 127;
    expD_t[d][j0] = (d == 0) ? 0.0f : __expf(logD[j0 * 128 + d]);
  }
  if (tid < 2 * SROW) (&s_lds[0][0])[tid] = 0.0f;
  if (tid < 16) m_lds[tid >> 3][tid & 7] = 1.0f;

  // ---- per-thread constants: exp(log_A) for i in [32c, 32c+32) ----
  float aA[16], aB[16];
#pragma unroll
  for (int k = 0; k < 16; ++k) {
    aA[k] = __expf(logA[(32 * c + k) * KST + jj]);
    aB[k] = __expf(logA[(32 * c + 16 + k) * KST + jj]);
  }
  const float expD0 = __expf(logD[jj * 128 + 0]);
  const float pexp  = __expf(logpi[jj]);

  float QA[16], QB[16];
#pragma unroll
  for (int k = 0; k < 16; ++k) { QA[k] = 0.0f; QB[k] = 0.0f; }

  __syncthreads();  // table + buffers ready (full drain once is fine)

  // expD window init for t=0: eA[k] = expD[(-(32c+k))&127], eB: +16
  float eA[16], eB[16];
#pragma unroll
  for (int k = 0; k < 16; ++k) {
    eA[k] = expD_t[(-(32 * c + k)) & 127][jj];
    eB[k] = expD_t[(-(32 * c + 16 + k)) & 127][jj];
  }

  // log_B prefetch ring (16 ahead)
  float lb[16];
#pragma unroll
  for (int u = 0; u < 16; ++u) lb[u] = pB[(size_t)u * KST];

  float psi    = 1.0f;
  float invpsi = 1.0f;
  float Ctot   = 0.0f;
  float s_keep = 0.0f;
  float exq    = __expf(lb[0]);   // emission factor for step 0

#pragma unroll 1
  for (int t0 = 0; t0 < T_LEN; t0 += 16) {
#define STEP(U) step_body<U>(t0, c, jj, w, L, pB, QA, QB, aA, aB, eA, eB, lb, \
                             psi, invpsi, exq, Ctot, s_keep, expD0, pexp,      \
                             s_lds, m_lds, expD_t)
    STEP(0);  STEP(1);  STEP(2);  STEP(3);
    STEP(4);  STEP(5);  STEP(6);  STEP(7);
    STEP(8);  STEP(9);  STEP(10); STEP(11);
    STEP(12); STEP(13); STEP(14); STEP(15);
#undef STEP
  }

  // ---- final: out[b] = Ctot + log sum_j shat[j] (count each state once) ---
  float v = (c == 0) ? s_keep : 0.0f;
  v += __shfl_xor(v, 1);  v += __shfl_xor(v, 2);
  v += __shfl_xor(v, 4);  v += __shfl_xor(v, 8);
  v += __shfl_xor(v, 16); v += __shfl_xor(v, 32);
  if (L == 0) fin[w] = v;
  __syncthreads();
  if (tid == 0) {
    float tot = 0.0f;
#pragma unroll
    for (int i = 0; i < 8; ++i) tot += fin[i];
    out[b] = Ctot + __logf(tot);
  }
}

extern "C" void kernel_launch(void* const* d_in, const int* in_sizes, int n_in,
                              void* d_out, int out_size, void* d_ws, size_t ws_size,
                              hipStream_t stream) {
  const float* logB  = (const float*)d_in[0];
  const float* logpi = (const float*)d_in[1];
  const float* logA  = (const float*)d_in[2];
  const float* logD  = (const float*)d_in[3];
  float* out = (float*)d_out;
  const int B = out_size;  // 32
  hipLaunchKernelGGL(hsmm_fwd_kernel, dim3(B), dim3(NTHR), 0, stream,
                     logB, logpi, logA, logD, out);
}